// Round 15
// baseline (285.154 us; speedup 1.0000x reference)
//
#include <hip/hip_runtime.h>
#include <math.h>

// ---------------------------------------------------------------------------
// R15: (1) prep MG=1 (3126 blocks, half regs -> latency hiding);
//      (2) big stage batched across mp via blockIdx.z (Tbig/AGbig per-mp) --
//          two 19%-occupancy aggsc dispatches overlap into one.
// RNG verified R3. C/D layout (m89): col=lane&15, row=(lane>>4)*4+reg.
// ---------------------------------------------------------------------------

typedef __attribute__((ext_vector_type(8))) short bf16x8;
typedef __attribute__((ext_vector_type(4))) float f32x4;

__device__ __forceinline__ float b2f(unsigned short u) {
  union { unsigned u; float f; } c; c.u = ((unsigned)u) << 16; return c.f;
}
__device__ __forceinline__ unsigned short f2b(float f) {
  union { float f; unsigned u; } c; c.f = f;
  return (unsigned short)((c.u + 0x7FFFu + ((c.u >> 16) & 1u)) >> 16);
}

// tanh with PRE-SCALED input (x already multiplied by 2*log2(e) via weights).
__device__ __forceinline__ float fast_tanh_pre(float x) {
  float z; asm("v_exp_f32 %0, %1" : "=v"(z) : "v"(x));
  float zp1 = z + 1.f;
  float w; asm("v_rcp_f32 %0, %1" : "=v"(w) : "v"(zp1));
  return fmaf(-2.f, w, 1.f);
}
__device__ __forceinline__ float fast_exp(float x) {
  float y = x * 1.4426950408889634f;
  float z; asm("v_exp_f32 %0, %1" : "=v"(z) : "v"(y));
  return z;
}

__host__ __device__ __forceinline__ void tf2x32(unsigned k0, unsigned k1,
                                                unsigned x0, unsigned x1,
                                                unsigned& o0, unsigned& o1) {
  const unsigned ks2 = k0 ^ k1 ^ 0x1BD11BDAu;
  unsigned v0 = x0 + k0, v1 = x1 + k1;
#define TFR(r) { v0 += v1; v1 = (v1 << (r)) | (v1 >> (32 - (r))); v1 ^= v0; }
  TFR(13) TFR(15) TFR(26) TFR(6)
  v0 += k1;  v1 += ks2 + 1u;
  TFR(17) TFR(29) TFR(16) TFR(24)
  v0 += ks2; v1 += k0 + 2u;
  TFR(13) TFR(15) TFR(26) TFR(6)
  v0 += k0;  v1 += k1 + 3u;
  TFR(17) TFR(29) TFR(16) TFR(24)
  v0 += k1;  v1 += ks2 + 4u;
  TFR(13) TFR(15) TFR(26) TFR(6)
  v0 += ks2; v1 += k0 + 5u;
#undef TFR
  o0 = v0; o1 = v1;
}

// batched 2-hop frontier: blockIdx.z = mp
__global__ void frontier2_kernel(const int* __restrict__ adjs,
                                 const int* __restrict__ ids,
                                 int* __restrict__ nodes_all,
                                 unsigned a00, unsigned a01, unsigned b00, unsigned b01,
                                 unsigned a10, unsigned a11, unsigned b10, unsigned b11) {
  const int mp = blockIdx.z;
  const int* adj = adjs + (size_t)mp * 6400000;
  int* nodes = nodes_all + (size_t)mp * 139776;
  unsigned k0a = mp ? a10 : a00, k1a = mp ? a11 : a01;
  unsigned k0b = mp ? b10 : b00, k1b = mp ? b11 : b01;
  int i = blockIdx.x * 256 + threadIdx.x;
  int j = i >> 4;
  unsigned y0, y1;
  tf2x32(k0a, k1a, 0u, (unsigned)j, y0, y1);
  int col1 = (int)((y0 ^ y1) & 31u);
  int p0 = ids[j >> 4];
  int f1 = adj[(size_t)p0 * 32 + col1];
  tf2x32(k0b, k1b, 0u, (unsigned)i, y0, y1);
  int col2 = (int)((y0 ^ y1) & 31u);
  int f2 = adj[(size_t)f1 * 32 + col2];
  nodes[8704 + i] = f2;
  if ((i & 15) == 0) nodes[512 + j] = f1;
  if (i < 512) nodes[i] = ids[i];
}

// ---------------------------------------------------------------------------
// transcast: Wa1 ranges scaled by 2*log2(e) (tanh prescale); others plain.
// ---------------------------------------------------------------------------
__global__ void transcast_kernel(const float* __restrict__ Wp,
                                 const float* __restrict__ Wa1_0,
                                 const float* __restrict__ Wa1_1,
                                 const float* __restrict__ Wx_0,
                                 const float* __restrict__ Wn_0,
                                 const float* __restrict__ Wx_1,
                                 const float* __restrict__ Wn_1,
                                 unsigned short* __restrict__ Wpt) {
  const float TS = 2.8853900817779268f;   // 2*log2(e)
  int o = blockIdx.x * 256 + threadIdx.x;
  if (o >= 1196032) return;
  float v;
  if (o < 16384) {
    int k = o & 127, c = o >> 7;
    v = Wp[k * 128 + c];
  } else if (o < 278528) {
    int o2 = o - 16384;
    int k = o2 & 127, c = (o2 >> 7) & 127, h = (o2 >> 14) & 3,
        half = (o2 >> 16) & 1, mpi = o2 >> 17;
    v = TS * Wa1_0[(((size_t)(mpi * 4 + h) * 256) + half * 128 + k) * 128 + c];
  } else if (o < 802816) {
    int o3 = o - 278528;
    int k = o3 & 255, c = (o3 >> 8) & 127, h = (o3 >> 15) & 3,
        half = (o3 >> 17) & 1, mpi = o3 >> 18;
    v = TS * Wa1_1[(((size_t)(mpi * 4 + h) * 512) + half * 256 + k) * 128 + c];
  } else if (o < 868352) {
    int o4 = o - 802816;
    int k = o4 & 127, oo = (o4 >> 7) & 63, h = (o4 >> 13) & 3, mpi = o4 >> 15;
    v = Wx_0[(((size_t)(mpi * 4 + h) * 128) + k) * 64 + oo];
  } else if (o < 933888) {
    int o4 = o - 868352;
    int k = o4 & 127, oo = (o4 >> 7) & 63, h = (o4 >> 13) & 3, mpi = o4 >> 15;
    v = Wn_0[(((size_t)(mpi * 4 + h) * 128) + k) * 64 + oo];
  } else if (o < 1064960) {
    int o5 = o - 933888;
    int k = o5 & 255, oo = (o5 >> 8) & 63, h = (o5 >> 14) & 3, mpi = o5 >> 16;
    v = Wx_1[(((size_t)(mpi * 4 + h) * 256) + k) * 64 + oo];
  } else {
    int o5 = o - 1064960;
    int k = o5 & 255, oo = (o5 >> 8) & 63, h = (o5 >> 14) & 3, mpi = o5 >> 16;
    v = Wn_1[(((size_t)(mpi * 4 + h) * 256) + k) * 64 + oo];
  }
  Wpt[o] = f2b(v);
}

// ---------------------------------------------------------------------------
// MFMA GEMM: block = (4*MG*16) rows x 128 cols, 4 waves x MG row-groups.
// MODE 0: bf16 C (prep: A fp32, clamped rows)  MODE 1: f32 C at col hb*128.
// ---------------------------------------------------------------------------
template <int MODE, bool A_F32, int NKS, int MG>
__global__ __launch_bounds__(256) void mfma_gemm(
    const void* __restrict__ Av, const int* __restrict__ gather,
    const unsigned short* __restrict__ WT, void* __restrict__ Cv,
    int ldc, int mclamp, int a_str, int g_str, int w_str, int c_str) {
  constexpr int K = NKS * 32;
  const int t = threadIdx.x;
  const int w = t >> 6, l = t & 63;
  const int lr = l & 15, lg = l >> 4;
  const int hb = blockIdx.y;
  const int mp = blockIdx.z;
  const int rbase = blockIdx.x * (4 * MG * 16) + w * (MG * 16);

  const unsigned short* Wb = WT + (size_t)mp * w_str + (size_t)hb * 128 * K;
  f32x4 acc[MG][8] = {};

  int arow[MG];
#pragma unroll
  for (int mg = 0; mg < MG; ++mg) {
    int row = rbase + mg * 16 + lr;
    arow[mg] = gather ? gather[(size_t)mp * g_str + row] : min(row, mclamp);
  }
  const float* Af = (const float*)Av;
  const unsigned short* Ab = ((const unsigned short*)Av) + (size_t)mp * a_str;

#pragma unroll
  for (int ks = 0; ks < NKS; ++ks) {
    const int koff = ks * 32 + lg * 8;
    bf16x8 a[MG], b[8];
#pragma unroll
    for (int mg = 0; mg < MG; ++mg) {
      if (A_F32) {
        const float* p = Af + (size_t)arow[mg] * K + koff;
        float4 v0 = *(const float4*)p;
        float4 v1 = *(const float4*)(p + 4);
        union { short s[8]; bf16x8 v; } u;
        u.s[0] = (short)f2b(v0.x); u.s[1] = (short)f2b(v0.y);
        u.s[2] = (short)f2b(v0.z); u.s[3] = (short)f2b(v0.w);
        u.s[4] = (short)f2b(v1.x); u.s[5] = (short)f2b(v1.y);
        u.s[6] = (short)f2b(v1.z); u.s[7] = (short)f2b(v1.w);
        a[mg] = u.v;
      } else {
        a[mg] = *(const bf16x8*)(Ab + (size_t)arow[mg] * K + koff);
      }
    }
#pragma unroll
    for (int f = 0; f < 8; ++f)
      b[f] = *(const bf16x8*)(Wb + (size_t)(f * 16 + lr) * K + koff);
#pragma unroll
    for (int mg = 0; mg < MG; ++mg)
#pragma unroll
      for (int f = 0; f < 8; ++f)
        acc[mg][f] = __builtin_amdgcn_mfma_f32_16x16x32_bf16(a[mg], b[f], acc[mg][f], 0, 0, 0);
  }

  if (MODE == 0) {
    unsigned short* Cb = ((unsigned short*)Cv) + (size_t)mp * c_str;
#pragma unroll
    for (int mg = 0; mg < MG; ++mg)
#pragma unroll
      for (int f = 0; f < 8; ++f)
#pragma unroll
        for (int r = 0; r < 4; ++r)
          Cb[(size_t)(rbase + mg * 16 + lg * 4 + r) * ldc + f * 16 + lr] =
              f2b(acc[mg][f][r]);
  } else {
    float* Cf = ((float*)Cv) + (size_t)mp * c_str;
#pragma unroll
    for (int mg = 0; mg < MG; ++mg)
#pragma unroll
      for (int f = 0; f < 8; ++f)
#pragma unroll
        for (int r = 0; r < 4; ++r)
          Cf[(size_t)(rbase + mg * 16 + lg * 4 + r) * ldc + hb * 128 + f * 16 + lr] =
              acc[mg][f][r];
  }
}

// ---------------------------------------------------------------------------
// AGGSC+AGG fused: grid (M/(MG*16), 1, nmp); block = 4 waves = 4 heads
// sharing an LDS-staged (MG*16)-row NB tile (gather-capable).
// 2-pass column split, sequential halves (no spill).
// ---------------------------------------------------------------------------
template <int NKS, int MG>
__global__ __launch_bounds__(256, 2) void aggsc_mfma(
    const unsigned short* __restrict__ NB, const int* __restrict__ gather,
    const float* __restrict__ Tb, const unsigned short* __restrict__ WTbot,
    const float* __restrict__ wa2, unsigned short* __restrict__ AG,
    int nb_str, int g_str, int t_str, int w_str, int wa2_str, int ag_str) {
  constexpr int K = NKS * 32;
  constexpr int KP = K + 8;
  constexpr int ROWS = MG * 16;
  const int t = threadIdx.x;
  const int w = t >> 6, l = t & 63;          // w = head
  const int lr = l & 15, lg = l >> 4;
  const int mp = blockIdx.z;
  const int rbase = blockIdx.x * ROWS;

  __shared__ unsigned short NBs[ROWS * KP];
  __shared__ float alsh[4][MG][16];

  const unsigned short* NBm = NB + (size_t)mp * nb_str;
  const int* gm = gather ? gather + (size_t)mp * g_str : nullptr;

  constexpr int CH = (ROWS * K) / (256 * 8);
#pragma unroll
  for (int q = 0; q < CH; ++q) {
    int c = q * 256 + t;
    int row = c / (K / 8), kc = c % (K / 8);
    int src = gm ? gm[rbase + row] : (rbase + row);
    bf16x8 v = *(const bf16x8*)(NBm + (size_t)src * K + kc * 8);
    *(bf16x8*)(&NBs[row * KP + kc * 8]) = v;
  }
  __syncthreads();

  const unsigned short* Wb = WTbot + (size_t)mp * w_str + (size_t)w * 128 * K;
  float sc[MG][4];
#pragma unroll
  for (int mg = 0; mg < MG; ++mg)
#pragma unroll
    for (int r = 0; r < 4; ++r) sc[mg][r] = 0.f;

#pragma unroll 1
  for (int half = 0; half < 2; ++half) {
    f32x4 acc[MG][4] = {};
#pragma unroll
    for (int ks = 0; ks < NKS; ++ks) {
      const int koff = ks * 32 + lg * 8;
      bf16x8 a[MG], b[4];
#pragma unroll
      for (int f = 0; f < 4; ++f)
        b[f] = *(const bf16x8*)(Wb + (size_t)(half * 64 + f * 16 + lr) * K + koff);
#pragma unroll
      for (int mg = 0; mg < MG; ++mg)
        a[mg] = *(const bf16x8*)(&NBs[(mg * 16 + lr) * KP + koff]);
#pragma unroll
      for (int mg = 0; mg < MG; ++mg)
#pragma unroll
        for (int f = 0; f < 4; ++f)
          acc[mg][f] = __builtin_amdgcn_mfma_f32_16x16x32_bf16(a[mg], b[f], acc[mg][f], 0, 0, 0);
    }
    float w2h[4];
#pragma unroll
    for (int f = 0; f < 4; ++f)
      w2h[f] = wa2[(size_t)mp * wa2_str + w * 128 + half * 64 + f * 16 + lr];
#pragma unroll
    for (int mg = 0; mg < MG; ++mg) {
      const int i = blockIdx.x * MG + mg;
      float tvh[4];
#pragma unroll
      for (int f = 0; f < 4; ++f)
        tvh[f] = Tb[(size_t)mp * t_str + (size_t)i * 512 + w * 128 + half * 64 + f * 16 + lr];
#pragma unroll
      for (int r = 0; r < 4; ++r) {
        float s = 0.f;
#pragma unroll
        for (int f = 0; f < 4; ++f)
          s += fast_tanh_pre(acc[mg][f][r] + tvh[f]) * w2h[f];
        sc[mg][r] += s;
      }
    }
  }

#pragma unroll
  for (int mg = 0; mg < MG; ++mg) {
    float s0 = sc[mg][0], s1 = sc[mg][1], s2 = sc[mg][2], s3 = sc[mg][3];
    s0 += __shfl_xor(s0, 1); s0 += __shfl_xor(s0, 2); s0 += __shfl_xor(s0, 4); s0 += __shfl_xor(s0, 8);
    s1 += __shfl_xor(s1, 1); s1 += __shfl_xor(s1, 2); s1 += __shfl_xor(s1, 4); s1 += __shfl_xor(s1, 8);
    s2 += __shfl_xor(s2, 1); s2 += __shfl_xor(s2, 2); s2 += __shfl_xor(s2, 4); s2 += __shfl_xor(s2, 8);
    s3 += __shfl_xor(s3, 1); s3 += __shfl_xor(s3, 2); s3 += __shfl_xor(s3, 4); s3 += __shfl_xor(s3, 8);
    float mx = fmaxf(fmaxf(s0, s1), fmaxf(s2, s3));
    mx = fmaxf(mx, __shfl_xor(mx, 16));
    mx = fmaxf(mx, __shfl_xor(mx, 32));
    float e0 = fast_exp(s0 - mx), e1 = fast_exp(s1 - mx);
    float e2 = fast_exp(s2 - mx), e3 = fast_exp(s3 - mx);
    float sum = e0 + e1 + e2 + e3;
    sum += __shfl_xor(sum, 16); sum += __shfl_xor(sum, 32);
    float inv = 1.f / sum;
    if (lr == 0) {
      alsh[w][mg][lg * 4 + 0] = e0 * inv;
      alsh[w][mg][lg * 4 + 1] = e1 * inv;
      alsh[w][mg][lg * 4 + 2] = e2 * inv;
      alsh[w][mg][lg * 4 + 3] = e3 * inv;
    }
  }
  // no barrier: wave reads only its own alsh[w]; NBs read-only after stage.

  constexpr int NCH = K >> 7;
#pragma unroll
  for (int mg = 0; mg < MG; ++mg) {
    const int i = blockIdx.x * MG + mg;
    float al[16];
#pragma unroll
    for (int s = 0; s < 16; ++s) al[s] = alsh[w][mg][s];
#pragma unroll
    for (int c = 0; c < NCH; ++c) {
      const int d = l * 2 + c * 128;
      float a0 = 0.f, a1 = 0.f;
#pragma unroll
      for (int s = 0; s < 16; ++s) {
        unsigned v = *(const unsigned*)(&NBs[(mg * 16 + s) * KP + d]);
        a0 = fmaf(al[s], b2f((unsigned short)(v & 0xffffu)), a0);
        a1 = fmaf(al[s], b2f((unsigned short)(v >> 16)), a1);
      }
      unsigned o = (unsigned)f2b(a0) | ((unsigned)f2b(a1) << 16);
      *(unsigned*)(AG + (size_t)mp * ag_str + ((size_t)i * 4 + w) * K + d) = o;
    }
  }
}

// ---------------------------------------------------------------------------
// OUTG: out[m, hb*64+c] = relu(x@Wx[hb] + agg[hb]@Wn[hb]); X optionally
// gathered. block = 4 waves x MG*16 rows. blockIdx.z = mp.
// ---------------------------------------------------------------------------
template <int DX, bool OUTB, int MG>
__global__ __launch_bounds__(256) void outg_kernel(
    const unsigned short* __restrict__ Xb, const int* __restrict__ gatherX,
    const unsigned short* __restrict__ AG,
    const unsigned short* __restrict__ WXT, const unsigned short* __restrict__ WNT,
    void* __restrict__ outv,
    int x_str, int g_str, int ag_str, int w_str, int o_str) {
  const int t = threadIdx.x;
  const int w = t >> 6, l = t & 63;
  const int lr = l & 15, lg = l >> 4;
  const int hb = blockIdx.y;
  const int mp = blockIdx.z;
  const int rbase = blockIdx.x * (4 * MG * 16) + w * (MG * 16);
  f32x4 acc[MG][4] = {};
  constexpr int nks = DX >> 5;

  const unsigned short* Xm = Xb + (size_t)mp * x_str;
  const int* gm = gatherX ? gatherX + (size_t)mp * g_str : nullptr;
  const unsigned short* AGm = AG + (size_t)mp * ag_str;
  const unsigned short* WXm = WXT + (size_t)mp * w_str;
  const unsigned short* WNm = WNT + (size_t)mp * w_str;

  int xrow[MG];
#pragma unroll
  for (int mg = 0; mg < MG; ++mg) {
    int row = rbase + mg * 16 + lr;
    xrow[mg] = gm ? gm[row] : row;
  }

#pragma unroll
  for (int ks = 0; ks < nks; ++ks) {
    const int koff = ks * 32 + lg * 8;
    bf16x8 a[MG], b[4];
#pragma unroll
    for (int mg = 0; mg < MG; ++mg)
      a[mg] = *(const bf16x8*)(Xm + (size_t)xrow[mg] * DX + koff);
#pragma unroll
    for (int f = 0; f < 4; ++f)
      b[f] = *(const bf16x8*)(WXm + (size_t)(hb * 64 + f * 16 + lr) * DX + koff);
#pragma unroll
    for (int mg = 0; mg < MG; ++mg)
#pragma unroll
      for (int f = 0; f < 4; ++f)
        acc[mg][f] = __builtin_amdgcn_mfma_f32_16x16x32_bf16(a[mg], b[f], acc[mg][f], 0, 0, 0);
  }
#pragma unroll
  for (int ks = 0; ks < nks; ++ks) {
    const int koff = ks * 32 + lg * 8;
    bf16x8 a[MG], b[4];
#pragma unroll
    for (int mg = 0; mg < MG; ++mg)
      a[mg] = *(const bf16x8*)(AGm + ((size_t)(rbase + mg * 16 + lr) * 4 + hb) * DX + koff);
#pragma unroll
    for (int f = 0; f < 4; ++f)
      b[f] = *(const bf16x8*)(WNm + (size_t)(hb * 64 + f * 16 + lr) * DX + koff);
#pragma unroll
    for (int mg = 0; mg < MG; ++mg)
#pragma unroll
      for (int f = 0; f < 4; ++f)
        acc[mg][f] = __builtin_amdgcn_mfma_f32_16x16x32_bf16(a[mg], b[f], acc[mg][f], 0, 0, 0);
  }

#pragma unroll
  for (int mg = 0; mg < MG; ++mg)
#pragma unroll
    for (int f = 0; f < 4; ++f)
#pragma unroll
      for (int r = 0; r < 4; ++r) {
        float v = fmaxf(acc[mg][f][r], 0.f);
        size_t idx = (size_t)mp * o_str +
                     (size_t)(rbase + mg * 16 + lg * 4 + r) * 256 + hb * 64 + f * 16 + lr;
        if (OUTB) ((unsigned short*)outv)[idx] = f2b(v);
        else      ((float*)outv)[idx] = v;
      }
}

// ---------------------------------------------------------------------------
extern "C" void kernel_launch(void* const* d_in, const int* in_sizes, int n_in,
                              void* d_out, int out_size, void* d_ws, size_t ws_size,
                              hipStream_t stream) {
  (void)in_sizes; (void)n_in; (void)out_size; (void)ws_size;
  const int*   ids   = (const int*)d_in[0];
  const float* feats = (const float*)d_in[1];
  const int*   adjs  = (const int*)d_in[2];
  const float* Wp    = (const float*)d_in[3];
  const float* Wa1_0 = (const float*)d_in[4];
  const float* wa2_0 = (const float*)d_in[5];
  const float* Wx_0  = (const float*)d_in[6];
  const float* Wn_0  = (const float*)d_in[7];
  const float* Wa1_1 = (const float*)d_in[8];
  const float* wa2_1 = (const float*)d_in[9];
  const float* Wx_1  = (const float*)d_in[10];
  const float* Wn_1  = (const float*)d_in[11];
  float* out = (float*)d_out;

  char* ws = (char*)d_ws;
  size_t off = 0;
  auto alloc = [&](size_t bytes) { char* p = ws + off; off += (bytes + 255) & ~(size_t)255; return p; };
  int*            nodes = (int*)alloc((size_t)2 * 139776 * 4);
  unsigned short* P_all = (unsigned short*)alloc((size_t)200064 * 128 * 2);
  float*          Tbig  = (float*)alloc((size_t)2 * 8192 * 512 * 4);
  float*          T2    = (float*)alloc((size_t)2 * 512 * 512 * 4);
  unsigned short* AGbig = (unsigned short*)alloc((size_t)2 * 8192 * 4 * 128 * 2);
  unsigned short* AG2   = (unsigned short*)alloc((size_t)2 * 512 * 4 * 256 * 2);
  unsigned short* NF1b  = (unsigned short*)alloc((size_t)2 * 8192 * 256 * 2);
  unsigned short* NF0b  = (unsigned short*)alloc((size_t)2 * 512 * 256 * 2);
  unsigned short* WB    = (unsigned short*)alloc((size_t)1196032 * 2);

  unsigned short* Wpt  = WB;
  unsigned short* WT0  = WB + 16384;
  unsigned short* WT1  = WB + 278528;
  unsigned short* WXT0 = WB + 802816;
  unsigned short* WNT0 = WB + 868352;
  unsigned short* WXT1 = WB + 933888;
  unsigned short* WNT1 = WB + 1064960;

  const int BIG = 1 << 30;

  unsigned key0[2][2], key1[2][2];
  for (int mp = 0; mp < 2; ++mp)
    for (int li = 0; li < 2; ++li) {
      unsigned K0, K1;
      tf2x32(0u, 42u, 0u, (unsigned)(mp * 16 + li), K0, K1);
      tf2x32(K0, K1, 0u, 1u, key0[mp][li], key1[mp][li]);
    }

  transcast_kernel<<<4672, 256, 0, stream>>>(Wp, Wa1_0, Wa1_1, Wx_0, Wn_0,
                                             Wx_1, Wn_1, WB);
  frontier2_kernel<<<dim3(512, 1, 2), 256, 0, stream>>>(
      adjs, ids, nodes,
      key0[0][0], key1[0][0], key0[0][1], key1[0][1],
      key0[1][0], key1[1][0], key0[1][1], key1[1][1]);

  // prep ALL nodes once: P_all = bf16(feats @ Wp). MG=1 -> 3126 blocks (TLP).
  mfma_gemm<0, true, 4, 1><<<dim3(3126, 1, 1), 256, 0, stream>>>(
      feats, nullptr, Wpt, P_all, 128, 199999, 0, 0, 0, 0);

  // ---- big stage (L0 agg B), BATCHED across mp via blockIdx.z:
  //      x = frontier1 (gather), nb = frontier2 (gather) -> NF1b[mp]
  mfma_gemm<1, false, 4, 2><<<dim3(64, 4, 2), 256, 0, stream>>>(
      P_all, nodes + 512, WT0, Tbig, 512, BIG,
      0, 139776, 131072, 4194304);
  aggsc_mfma<4, 4><<<dim3(2048, 1, 2), 256, 0, stream>>>(
      P_all, nodes + 8704, Tbig, WT0 + 65536, wa2_0, AGbig,
      0, 139776, 4194304, 131072, 512, 4194304);
  outg_kernel<128, true, 2><<<dim3(64, 4, 2), 256, 0, stream>>>(
      P_all, nodes + 512, AGbig, WXT0, WNT0, NF1b,
      0, 139776, 4194304, 32768, 2097152);

  // ---- L0 agg A (batched): x=P_all[ids], nb=P_all[frontier1] -> NF0b
  mfma_gemm<1, false, 4, 1><<<dim3(8, 4, 2), 256, 0, stream>>>(
      P_all, nodes, WT0, T2, 512, BIG, 0, 139776, 131072, 262144);
  aggsc_mfma<4, 2><<<dim3(256, 1, 2), 256, 0, stream>>>(
      P_all, nodes + 512, T2, WT0 + 65536, wa2_0, AG2,
      0, 139776, 262144, 131072, 512, 262144);
  outg_kernel<128, true, 1><<<dim3(8, 4, 2), 256, 0, stream>>>(
      P_all, nodes, AG2, WXT0, WNT0, NF0b, 0, 139776, 262144, 32768, 131072);

  // ---- L1 (batched): x=NF0b, nb=NF1b -> d_out
  mfma_gemm<1, false, 8, 1><<<dim3(8, 4, 2), 256, 0, stream>>>(
      NF0b, nullptr, WT1, T2, 512, 511, 131072, 0, 262144, 262144);
  aggsc_mfma<8, 2><<<dim3(256, 1, 2), 256, 0, stream>>>(
      NF1b, nullptr, T2, WT1 + 131072, wa2_1, AG2,
      2097152, 0, 262144, 262144, 512, 524288);
  outg_kernel<256, false, 1><<<dim3(8, 4, 2), 256, 0, stream>>>(
      NF0b, nullptr, AG2, WXT1, WNT1, out, 131072, 0, 524288, 65536, 131072);
}

// Round 17
// 272.388 us; speedup vs baseline: 1.0469x; 1.0469x over previous
//
#include <hip/hip_runtime.h>
#include <math.h>

// ---------------------------------------------------------------------------
// R17 = R16 with the L1 aggsc grid bug fixed (16 -> 256 blocks; NF1b has
// 8192 NB rows / 32 rows per block).
//  (1) aggsc AG phase uses b128 LDS reads (lane owns 8-d chunk; MG*K=512);
//  (2) L0A small-stage work merged INTO the big-stage dispatches as extra
//      blockIdx.x segments (T/aggsc/outg each handle 2 segments).
// RNG verified R3. C/D layout (m89): col=lane&15, row=(lane>>4)*4+reg.
// ---------------------------------------------------------------------------

typedef __attribute__((ext_vector_type(8))) short bf16x8;
typedef __attribute__((ext_vector_type(4))) float f32x4;

__device__ __forceinline__ float b2f(unsigned short u) {
  union { unsigned u; float f; } c; c.u = ((unsigned)u) << 16; return c.f;
}
__device__ __forceinline__ unsigned short f2b(float f) {
  union { float f; unsigned u; } c; c.f = f;
  return (unsigned short)((c.u + 0x7FFFu + ((c.u >> 16) & 1u)) >> 16);
}

// tanh with PRE-SCALED input (x already multiplied by 2*log2(e) via weights).
__device__ __forceinline__ float fast_tanh_pre(float x) {
  float z; asm("v_exp_f32 %0, %1" : "=v"(z) : "v"(x));
  float zp1 = z + 1.f;
  float w; asm("v_rcp_f32 %0, %1" : "=v"(w) : "v"(zp1));
  return fmaf(-2.f, w, 1.f);
}
__device__ __forceinline__ float fast_exp(float x) {
  float y = x * 1.4426950408889634f;
  float z; asm("v_exp_f32 %0, %1" : "=v"(z) : "v"(y));
  return z;
}

__host__ __device__ __forceinline__ void tf2x32(unsigned k0, unsigned k1,
                                                unsigned x0, unsigned x1,
                                                unsigned& o0, unsigned& o1) {
  const unsigned ks2 = k0 ^ k1 ^ 0x1BD11BDAu;
  unsigned v0 = x0 + k0, v1 = x1 + k1;
#define TFR(r) { v0 += v1; v1 = (v1 << (r)) | (v1 >> (32 - (r))); v1 ^= v0; }
  TFR(13) TFR(15) TFR(26) TFR(6)
  v0 += k1;  v1 += ks2 + 1u;
  TFR(17) TFR(29) TFR(16) TFR(24)
  v0 += ks2; v1 += k0 + 2u;
  TFR(13) TFR(15) TFR(26) TFR(6)
  v0 += k0;  v1 += k1 + 3u;
  TFR(17) TFR(29) TFR(16) TFR(24)
  v0 += k1;  v1 += ks2 + 4u;
  TFR(13) TFR(15) TFR(26) TFR(6)
  v0 += ks2; v1 += k0 + 5u;
#undef TFR
  o0 = v0; o1 = v1;
}

// batched 2-hop frontier: blockIdx.z = mp
__global__ void frontier2_kernel(const int* __restrict__ adjs,
                                 const int* __restrict__ ids,
                                 int* __restrict__ nodes_all,
                                 unsigned a00, unsigned a01, unsigned b00, unsigned b01,
                                 unsigned a10, unsigned a11, unsigned b10, unsigned b11) {
  const int mp = blockIdx.z;
  const int* adj = adjs + (size_t)mp * 6400000;
  int* nodes = nodes_all + (size_t)mp * 139776;
  unsigned k0a = mp ? a10 : a00, k1a = mp ? a11 : a01;
  unsigned k0b = mp ? b10 : b00, k1b = mp ? b11 : b01;
  int i = blockIdx.x * 256 + threadIdx.x;
  int j = i >> 4;
  unsigned y0, y1;
  tf2x32(k0a, k1a, 0u, (unsigned)j, y0, y1);
  int col1 = (int)((y0 ^ y1) & 31u);
  int p0 = ids[j >> 4];
  int f1 = adj[(size_t)p0 * 32 + col1];
  tf2x32(k0b, k1b, 0u, (unsigned)i, y0, y1);
  int col2 = (int)((y0 ^ y1) & 31u);
  int f2 = adj[(size_t)f1 * 32 + col2];
  nodes[8704 + i] = f2;
  if ((i & 15) == 0) nodes[512 + j] = f1;
  if (i < 512) nodes[i] = ids[i];
}

// ---------------------------------------------------------------------------
// transcast: Wa1 ranges scaled by 2*log2(e) (tanh prescale); others plain.
// ---------------------------------------------------------------------------
__global__ void transcast_kernel(const float* __restrict__ Wp,
                                 const float* __restrict__ Wa1_0,
                                 const float* __restrict__ Wa1_1,
                                 const float* __restrict__ Wx_0,
                                 const float* __restrict__ Wn_0,
                                 const float* __restrict__ Wx_1,
                                 const float* __restrict__ Wn_1,
                                 unsigned short* __restrict__ Wpt) {
  const float TS = 2.8853900817779268f;   // 2*log2(e)
  int o = blockIdx.x * 256 + threadIdx.x;
  if (o >= 1196032) return;
  float v;
  if (o < 16384) {
    int k = o & 127, c = o >> 7;
    v = Wp[k * 128 + c];
  } else if (o < 278528) {
    int o2 = o - 16384;
    int k = o2 & 127, c = (o2 >> 7) & 127, h = (o2 >> 14) & 3,
        half = (o2 >> 16) & 1, mpi = o2 >> 17;
    v = TS * Wa1_0[(((size_t)(mpi * 4 + h) * 256) + half * 128 + k) * 128 + c];
  } else if (o < 802816) {
    int o3 = o - 278528;
    int k = o3 & 255, c = (o3 >> 8) & 127, h = (o3 >> 15) & 3,
        half = (o3 >> 17) & 1, mpi = o3 >> 18;
    v = TS * Wa1_1[(((size_t)(mpi * 4 + h) * 512) + half * 256 + k) * 128 + c];
  } else if (o < 868352) {
    int o4 = o - 802816;
    int k = o4 & 127, oo = (o4 >> 7) & 63, h = (o4 >> 13) & 3, mpi = o4 >> 15;
    v = Wx_0[(((size_t)(mpi * 4 + h) * 128) + k) * 64 + oo];
  } else if (o < 933888) {
    int o4 = o - 868352;
    int k = o4 & 127, oo = (o4 >> 7) & 63, h = (o4 >> 13) & 3, mpi = o4 >> 15;
    v = Wn_0[(((size_t)(mpi * 4 + h) * 128) + k) * 64 + oo];
  } else if (o < 1064960) {
    int o5 = o - 933888;
    int k = o5 & 255, oo = (o5 >> 8) & 63, h = (o5 >> 14) & 3, mpi = o5 >> 16;
    v = Wx_1[(((size_t)(mpi * 4 + h) * 256) + k) * 64 + oo];
  } else {
    int o5 = o - 1064960;
    int k = o5 & 255, oo = (o5 >> 8) & 63, h = (o5 >> 14) & 3, mpi = o5 >> 16;
    v = Wn_1[(((size_t)(mpi * 4 + h) * 256) + k) * 64 + oo];
  }
  Wpt[o] = f2b(v);
}

// ---------------------------------------------------------------------------
// MFMA GEMM (prep + L1-T): block = 4 waves x MG*16 rows x 128 cols.
// MODE 0: bf16 C (A fp32, clamped rows)  MODE 1: f32 C at col hb*128.
// ---------------------------------------------------------------------------
template <int MODE, bool A_F32, int NKS, int MG>
__global__ __launch_bounds__(256) void mfma_gemm(
    const void* __restrict__ Av, const int* __restrict__ gather,
    const unsigned short* __restrict__ WT, void* __restrict__ Cv,
    int ldc, int mclamp, int a_str, int g_str, int w_str, int c_str) {
  constexpr int K = NKS * 32;
  const int t = threadIdx.x;
  const int w = t >> 6, l = t & 63;
  const int lr = l & 15, lg = l >> 4;
  const int hb = blockIdx.y;
  const int mp = blockIdx.z;
  const int rbase = blockIdx.x * (4 * MG * 16) + w * (MG * 16);

  const unsigned short* Wb = WT + (size_t)mp * w_str + (size_t)hb * 128 * K;
  f32x4 acc[MG][8] = {};

  int arow[MG];
#pragma unroll
  for (int mg = 0; mg < MG; ++mg) {
    int row = rbase + mg * 16 + lr;
    arow[mg] = gather ? gather[(size_t)mp * g_str + row] : min(row, mclamp);
  }
  const float* Af = (const float*)Av;
  const unsigned short* Ab = ((const unsigned short*)Av) + (size_t)mp * a_str;

#pragma unroll
  for (int ks = 0; ks < NKS; ++ks) {
    const int koff = ks * 32 + lg * 8;
    bf16x8 a[MG], b[8];
#pragma unroll
    for (int mg = 0; mg < MG; ++mg) {
      if (A_F32) {
        const float* p = Af + (size_t)arow[mg] * K + koff;
        float4 v0 = *(const float4*)p;
        float4 v1 = *(const float4*)(p + 4);
        union { short s[8]; bf16x8 v; } u;
        u.s[0] = (short)f2b(v0.x); u.s[1] = (short)f2b(v0.y);
        u.s[2] = (short)f2b(v0.z); u.s[3] = (short)f2b(v0.w);
        u.s[4] = (short)f2b(v1.x); u.s[5] = (short)f2b(v1.y);
        u.s[6] = (short)f2b(v1.z); u.s[7] = (short)f2b(v1.w);
        a[mg] = u.v;
      } else {
        a[mg] = *(const bf16x8*)(Ab + (size_t)arow[mg] * K + koff);
      }
    }
#pragma unroll
    for (int f = 0; f < 8; ++f)
      b[f] = *(const bf16x8*)(Wb + (size_t)(f * 16 + lr) * K + koff);
#pragma unroll
    for (int mg = 0; mg < MG; ++mg)
#pragma unroll
      for (int f = 0; f < 8; ++f)
        acc[mg][f] = __builtin_amdgcn_mfma_f32_16x16x32_bf16(a[mg], b[f], acc[mg][f], 0, 0, 0);
  }

  if (MODE == 0) {
    unsigned short* Cb = ((unsigned short*)Cv) + (size_t)mp * c_str;
#pragma unroll
    for (int mg = 0; mg < MG; ++mg)
#pragma unroll
      for (int f = 0; f < 8; ++f)
#pragma unroll
        for (int r = 0; r < 4; ++r)
          Cb[(size_t)(rbase + mg * 16 + lg * 4 + r) * ldc + f * 16 + lr] =
              f2b(acc[mg][f][r]);
  } else {
    float* Cf = ((float*)Cv) + (size_t)mp * c_str;
#pragma unroll
    for (int mg = 0; mg < MG; ++mg)
#pragma unroll
      for (int f = 0; f < 8; ++f)
#pragma unroll
        for (int r = 0; r < 4; ++r)
          Cf[(size_t)(rbase + mg * 16 + lg * 4 + r) * ldc + hb * 128 + f * 16 + lr] =
              acc[mg][f][r];
  }
}

// ---------------------------------------------------------------------------
// T-GEMM merged (two segments): bx<split -> {g1,C1}; else -> {g2,C2}.
// ---------------------------------------------------------------------------
template <int NKS, int MG>
__global__ __launch_bounds__(256) void tgemm_m(
    const unsigned short* __restrict__ A,
    const int* __restrict__ g1, const int* __restrict__ g2,
    const unsigned short* __restrict__ WT,
    float* __restrict__ C1, float* __restrict__ C2, int split,
    int g1_str, int g2_str, int w_str, int c1_str, int c2_str) {
  constexpr int K = NKS * 32;
  const int t = threadIdx.x;
  const int w = t >> 6, l = t & 63;
  const int lr = l & 15, lg = l >> 4;
  const int bx = blockIdx.x, hb = blockIdx.y, mp = blockIdx.z;

  const int* gm; float* Cf; int rb;
  if (bx < split) { gm = g1 + (size_t)mp * g1_str; Cf = C1 + (size_t)mp * c1_str; rb = bx * (4 * MG * 16); }
  else            { gm = g2 + (size_t)mp * g2_str; Cf = C2 + (size_t)mp * c2_str; rb = (bx - split) * (4 * MG * 16); }
  const int rbase = rb + w * (MG * 16);

  const unsigned short* Wb = WT + (size_t)mp * w_str + (size_t)hb * 128 * K;
  f32x4 acc[MG][8] = {};

  int arow[MG];
#pragma unroll
  for (int mg = 0; mg < MG; ++mg)
    arow[mg] = gm[rbase + mg * 16 + lr];

#pragma unroll
  for (int ks = 0; ks < NKS; ++ks) {
    const int koff = ks * 32 + lg * 8;
    bf16x8 a[MG], b[8];
#pragma unroll
    for (int mg = 0; mg < MG; ++mg)
      a[mg] = *(const bf16x8*)(A + (size_t)arow[mg] * K + koff);
#pragma unroll
    for (int f = 0; f < 8; ++f)
      b[f] = *(const bf16x8*)(Wb + (size_t)(f * 16 + lr) * K + koff);
#pragma unroll
    for (int mg = 0; mg < MG; ++mg)
#pragma unroll
      for (int f = 0; f < 8; ++f)
        acc[mg][f] = __builtin_amdgcn_mfma_f32_16x16x32_bf16(a[mg], b[f], acc[mg][f], 0, 0, 0);
  }

#pragma unroll
  for (int mg = 0; mg < MG; ++mg)
#pragma unroll
    for (int f = 0; f < 8; ++f)
#pragma unroll
      for (int r = 0; r < 4; ++r)
        Cf[(size_t)(rbase + mg * 16 + lg * 4 + r) * 512 + hb * 128 + f * 16 + lr] =
            acc[mg][f][r];
}

// ---------------------------------------------------------------------------
// AGGSC+AGG merged (two segments). grid (split+n2, 1, nmp); block = 4 waves
// = 4 heads sharing LDS-staged (MG*16)-row NB tile. 2-pass column split.
// AG phase: b128 LDS reads (lane owns 8-d chunk; requires MG*K == 512).
// ---------------------------------------------------------------------------
template <int NKS, int MG>
__global__ __launch_bounds__(256, 2) void aggsc_m(
    const unsigned short* __restrict__ NB, int nb_str,
    const int* __restrict__ g1, const int* __restrict__ g2,
    const float* __restrict__ T1, const float* __restrict__ T2v,
    const unsigned short* __restrict__ WTbot, const float* __restrict__ wa2,
    unsigned short* __restrict__ A1, unsigned short* __restrict__ A2v, int split,
    int g1_str, int g2_str, int t1_str, int t2_str,
    int w_str, int wa2_str, int a1_str, int a2_str) {
  constexpr int K = NKS * 32;
  constexpr int KP = K + 8;
  constexpr int ROWS = MG * 16;
  static_assert(MG * K == 512, "AG b128 lane mapping requires MG*K==512");
  const int t = threadIdx.x;
  const int w = t >> 6, l = t & 63;          // w = head
  const int lr = l & 15, lg = l >> 4;
  const int bx = blockIdx.x, mp = blockIdx.z;

  const int* gm; const float* Tb; unsigned short* AG; int ib;
  if (bx < split) {
    gm = g1 ? g1 + (size_t)mp * g1_str : nullptr;
    Tb = T1 + (size_t)mp * t1_str;
    AG = A1 + (size_t)mp * a1_str;
    ib = bx;
  } else {
    gm = g2 ? g2 + (size_t)mp * g2_str : nullptr;
    Tb = T2v + (size_t)mp * t2_str;
    AG = A2v + (size_t)mp * a2_str;
    ib = bx - split;
  }
  const int rbase = ib * ROWS;

  __shared__ unsigned short NBs[ROWS * KP];
  __shared__ float alsh[4][MG][16];

  const unsigned short* NBm = NB + (size_t)mp * nb_str;

  constexpr int CH = (ROWS * K) / (256 * 8);
#pragma unroll
  for (int q = 0; q < CH; ++q) {
    int c = q * 256 + t;
    int row = c / (K / 8), kc = c % (K / 8);
    int src = gm ? gm[rbase + row] : (rbase + row);
    bf16x8 v = *(const bf16x8*)(NBm + (size_t)src * K + kc * 8);
    *(bf16x8*)(&NBs[row * KP + kc * 8]) = v;
  }
  __syncthreads();

  const unsigned short* Wb = WTbot + (size_t)mp * w_str + (size_t)w * 128 * K;
  float sc[MG][4];
#pragma unroll
  for (int mg = 0; mg < MG; ++mg)
#pragma unroll
    for (int r = 0; r < 4; ++r) sc[mg][r] = 0.f;

#pragma unroll 1
  for (int half = 0; half < 2; ++half) {
    f32x4 acc[MG][4] = {};
#pragma unroll
    for (int ks = 0; ks < NKS; ++ks) {
      const int koff = ks * 32 + lg * 8;
      bf16x8 a[MG], b[4];
#pragma unroll
      for (int f = 0; f < 4; ++f)
        b[f] = *(const bf16x8*)(Wb + (size_t)(half * 64 + f * 16 + lr) * K + koff);
#pragma unroll
      for (int mg = 0; mg < MG; ++mg)
        a[mg] = *(const bf16x8*)(&NBs[(mg * 16 + lr) * KP + koff]);
#pragma unroll
      for (int mg = 0; mg < MG; ++mg)
#pragma unroll
        for (int f = 0; f < 4; ++f)
          acc[mg][f] = __builtin_amdgcn_mfma_f32_16x16x32_bf16(a[mg], b[f], acc[mg][f], 0, 0, 0);
    }
    float w2h[4];
#pragma unroll
    for (int f = 0; f < 4; ++f)
      w2h[f] = wa2[(size_t)mp * wa2_str + w * 128 + half * 64 + f * 16 + lr];
#pragma unroll
    for (int mg = 0; mg < MG; ++mg) {
      const int i = ib * MG + mg;
      float tvh[4];
#pragma unroll
      for (int f = 0; f < 4; ++f)
        tvh[f] = Tb[(size_t)i * 512 + w * 128 + half * 64 + f * 16 + lr];
#pragma unroll
      for (int r = 0; r < 4; ++r) {
        float s = 0.f;
#pragma unroll
        for (int f = 0; f < 4; ++f)
          s += fast_tanh_pre(acc[mg][f][r] + tvh[f]) * w2h[f];
        sc[mg][r] += s;
      }
    }
  }

#pragma unroll
  for (int mg = 0; mg < MG; ++mg) {
    float s0 = sc[mg][0], s1 = sc[mg][1], s2 = sc[mg][2], s3 = sc[mg][3];
    s0 += __shfl_xor(s0, 1); s0 += __shfl_xor(s0, 2); s0 += __shfl_xor(s0, 4); s0 += __shfl_xor(s0, 8);
    s1 += __shfl_xor(s1, 1); s1 += __shfl_xor(s1, 2); s1 += __shfl_xor(s1, 4); s1 += __shfl_xor(s1, 8);
    s2 += __shfl_xor(s2, 1); s2 += __shfl_xor(s2, 2); s2 += __shfl_xor(s2, 4); s2 += __shfl_xor(s2, 8);
    s3 += __shfl_xor(s3, 1); s3 += __shfl_xor(s3, 2); s3 += __shfl_xor(s3, 4); s3 += __shfl_xor(s3, 8);
    float mx = fmaxf(fmaxf(s0, s1), fmaxf(s2, s3));
    mx = fmaxf(mx, __shfl_xor(mx, 16));
    mx = fmaxf(mx, __shfl_xor(mx, 32));
    float e0 = fast_exp(s0 - mx), e1 = fast_exp(s1 - mx);
    float e2 = fast_exp(s2 - mx), e3 = fast_exp(s3 - mx);
    float sum = e0 + e1 + e2 + e3;
    sum += __shfl_xor(sum, 16); sum += __shfl_xor(sum, 32);
    float inv = 1.f / sum;
    if (lr == 0) {
      alsh[w][mg][lg * 4 + 0] = e0 * inv;
      alsh[w][mg][lg * 4 + 1] = e1 * inv;
      alsh[w][mg][lg * 4 + 2] = e2 * inv;
      alsh[w][mg][lg * 4 + 3] = e3 * inv;
    }
  }
  // no barrier: wave reads only its own alsh[w]; NBs read-only after stage.

  // AG phase (b128): lane owns 8-d chunk of one row-group.
  constexpr int LPM = 64 / MG;               // lanes per mg (== K/8)
  const int mgA = l / LPM, d0 = (l % LPM) * 8;
  const int iA = ib * MG + mgA;
  float ad[8] = {};
#pragma unroll
  for (int s = 0; s < 16; ++s) {
    float alv = alsh[w][mgA][s];
    bf16x8 v = *(const bf16x8*)(&NBs[(mgA * 16 + s) * KP + d0]);
#pragma unroll
    for (int q = 0; q < 8; ++q)
      ad[q] = fmaf(alv, b2f((unsigned short)v[q]), ad[q]);
  }
  union { short s[8]; bf16x8 v; } o;
#pragma unroll
  for (int q = 0; q < 8; ++q) o.s[q] = (short)f2b(ad[q]);
  *(bf16x8*)(AG + ((size_t)iA * 4 + w) * K + d0) = o.v;
}

// ---------------------------------------------------------------------------
// OUTG merged (two segments): relu(x@Wx[hb] + agg[hb]@Wn[hb]), bf16 out.
// ---------------------------------------------------------------------------
template <int DX, int MG>
__global__ __launch_bounds__(256) void outg_m(
    const unsigned short* __restrict__ Xb,
    const int* __restrict__ g1, const int* __restrict__ g2,
    const unsigned short* __restrict__ A1, const unsigned short* __restrict__ A2v,
    const unsigned short* __restrict__ WXT, const unsigned short* __restrict__ WNT,
    unsigned short* __restrict__ O1, unsigned short* __restrict__ O2, int split,
    int g1_str, int g2_str, int a1_str, int a2_str,
    int w_str, int o1_str, int o2_str) {
  const int t = threadIdx.x;
  const int w = t >> 6, l = t & 63;
  const int lr = l & 15, lg = l >> 4;
  const int bx = blockIdx.x, hb = blockIdx.y, mp = blockIdx.z;
  constexpr int nks = DX >> 5;

  const int* gm; const unsigned short* AGm; unsigned short* Om; int rb;
  if (bx < split) {
    gm = g1 + (size_t)mp * g1_str; AGm = A1 + (size_t)mp * a1_str;
    Om = O1 + (size_t)mp * o1_str; rb = bx * (4 * MG * 16);
  } else {
    gm = g2 + (size_t)mp * g2_str; AGm = A2v + (size_t)mp * a2_str;
    Om = O2 + (size_t)mp * o2_str; rb = (bx - split) * (4 * MG * 16);
  }
  const int rbase = rb + w * (MG * 16);
  const unsigned short* WXm = WXT + (size_t)mp * w_str;
  const unsigned short* WNm = WNT + (size_t)mp * w_str;
  f32x4 acc[MG][4] = {};

  int xrow[MG];
#pragma unroll
  for (int mg = 0; mg < MG; ++mg)
    xrow[mg] = gm[rbase + mg * 16 + lr];

#pragma unroll
  for (int ks = 0; ks < nks; ++ks) {
    const int koff = ks * 32 + lg * 8;
    bf16x8 a[MG], b[4];
#pragma unroll
    for (int mg = 0; mg < MG; ++mg)
      a[mg] = *(const bf16x8*)(Xb + (size_t)xrow[mg] * DX + koff);
#pragma unroll
    for (int f = 0; f < 4; ++f)
      b[f] = *(const bf16x8*)(WXm + (size_t)(hb * 64 + f * 16 + lr) * DX + koff);
#pragma unroll
    for (int mg = 0; mg < MG; ++mg)
#pragma unroll
      for (int f = 0; f < 4; ++f)
        acc[mg][f] = __builtin_amdgcn_mfma_f32_16x16x32_bf16(a[mg], b[f], acc[mg][f], 0, 0, 0);
  }
#pragma unroll
  for (int ks = 0; ks < nks; ++ks) {
    const int koff = ks * 32 + lg * 8;
    bf16x8 a[MG], b[4];
#pragma unroll
    for (int mg = 0; mg < MG; ++mg)
      a[mg] = *(const bf16x8*)(AGm + ((size_t)(rbase + mg * 16 + lr) * 4 + hb) * DX + koff);
#pragma unroll
    for (int f = 0; f < 4; ++f)
      b[f] = *(const bf16x8*)(WNm + (size_t)(hb * 64 + f * 16 + lr) * DX + koff);
#pragma unroll
    for (int mg = 0; mg < MG; ++mg)
#pragma unroll
      for (int f = 0; f < 4; ++f)
        acc[mg][f] = __builtin_amdgcn_mfma_f32_16x16x32_bf16(a[mg], b[f], acc[mg][f], 0, 0, 0);
  }

#pragma unroll
  for (int mg = 0; mg < MG; ++mg)
#pragma unroll
    for (int f = 0; f < 4; ++f)
#pragma unroll
      for (int r = 0; r < 4; ++r) {
        float v = fmaxf(acc[mg][f][r], 0.f);
        Om[(size_t)(rbase + mg * 16 + lg * 4 + r) * 256 + hb * 64 + f * 16 + lr] = f2b(v);
      }
}

// ---------------------------------------------------------------------------
// OUTG plain (L1, f32 out, no gather).
// ---------------------------------------------------------------------------
template <int DX, int MG>
__global__ __launch_bounds__(256) void outg_f32(
    const unsigned short* __restrict__ Xb, const unsigned short* __restrict__ AG,
    const unsigned short* __restrict__ WXT, const unsigned short* __restrict__ WNT,
    float* __restrict__ outv,
    int x_str, int ag_str, int w_str, int o_str) {
  const int t = threadIdx.x;
  const int w = t >> 6, l = t & 63;
  const int lr = l & 15, lg = l >> 4;
  const int hb = blockIdx.y, mp = blockIdx.z;
  const int rbase = blockIdx.x * (4 * MG * 16) + w * (MG * 16);
  constexpr int nks = DX >> 5;
  const unsigned short* Xm = Xb + (size_t)mp * x_str;
  const unsigned short* AGm = AG + (size_t)mp * ag_str;
  const unsigned short* WXm = WXT + (size_t)mp * w_str;
  const unsigned short* WNm = WNT + (size_t)mp * w_str;
  f32x4 acc[MG][4] = {};

#pragma unroll
  for (int ks = 0; ks < nks; ++ks) {
    const int koff = ks * 32 + lg * 8;
    bf16x8 a[MG], b[4];
#pragma unroll
    for (int mg = 0; mg < MG; ++mg)
      a[mg] = *(const bf16x8*)(Xm + (size_t)(rbase + mg * 16 + lr) * DX + koff);
#pragma unroll
    for (int f = 0; f < 4; ++f)
      b[f] = *(const bf16x8*)(WXm + (size_t)(hb * 64 + f * 16 + lr) * DX + koff);
#pragma unroll
    for (int mg = 0; mg < MG; ++mg)
#pragma unroll
      for (int f = 0; f < 4; ++f)
        acc[mg][f] = __builtin_amdgcn_mfma_f32_16x16x32_bf16(a[mg], b[f], acc[mg][f], 0, 0, 0);
  }
#pragma unroll
  for (int ks = 0; ks < nks; ++ks) {
    const int koff = ks * 32 + lg * 8;
    bf16x8 a[MG], b[4];
#pragma unroll
    for (int mg = 0; mg < MG; ++mg)
      a[mg] = *(const bf16x8*)(AGm + ((size_t)(rbase + mg * 16 + lr) * 4 + hb) * DX + koff);
#pragma unroll
    for (int f = 0; f < 4; ++f)
      b[f] = *(const bf16x8*)(WNm + (size_t)(hb * 64 + f * 16 + lr) * DX + koff);
#pragma unroll
    for (int mg = 0; mg < MG; ++mg)
#pragma unroll
      for (int f = 0; f < 4; ++f)
        acc[mg][f] = __builtin_amdgcn_mfma_f32_16x16x32_bf16(a[mg], b[f], acc[mg][f], 0, 0, 0);
  }

#pragma unroll
  for (int mg = 0; mg < MG; ++mg)
#pragma unroll
    for (int f = 0; f < 4; ++f)
#pragma unroll
      for (int r = 0; r < 4; ++r) {
        float v = fmaxf(acc[mg][f][r], 0.f);
        outv[(size_t)mp * o_str +
             (size_t)(rbase + mg * 16 + lg * 4 + r) * 256 + hb * 64 + f * 16 + lr] = v;
      }
}

// ---------------------------------------------------------------------------
extern "C" void kernel_launch(void* const* d_in, const int* in_sizes, int n_in,
                              void* d_out, int out_size, void* d_ws, size_t ws_size,
                              hipStream_t stream) {
  (void)in_sizes; (void)n_in; (void)out_size; (void)ws_size;
  const int*   ids   = (const int*)d_in[0];
  const float* feats = (const float*)d_in[1];
  const int*   adjs  = (const int*)d_in[2];
  const float* Wp    = (const float*)d_in[3];
  const float* Wa1_0 = (const float*)d_in[4];
  const float* wa2_0 = (const float*)d_in[5];
  const float* Wx_0  = (const float*)d_in[6];
  const float* Wn_0  = (const float*)d_in[7];
  const float* Wa1_1 = (const float*)d_in[8];
  const float* wa2_1 = (const float*)d_in[9];
  const float* Wx_1  = (const float*)d_in[10];
  const float* Wn_1  = (const float*)d_in[11];
  float* out = (float*)d_out;

  char* ws = (char*)d_ws;
  size_t off = 0;
  auto alloc = [&](size_t bytes) { char* p = ws + off; off += (bytes + 255) & ~(size_t)255; return p; };
  int*            nodes = (int*)alloc((size_t)2 * 139776 * 4);
  unsigned short* P_all = (unsigned short*)alloc((size_t)200064 * 128 * 2);
  float*          Tbig  = (float*)alloc((size_t)2 * 8192 * 512 * 4);
  float*          T2    = (float*)alloc((size_t)2 * 512 * 512 * 4);
  unsigned short* AGbig = (unsigned short*)alloc((size_t)2 * 8192 * 4 * 128 * 2);
  unsigned short* AG2   = (unsigned short*)alloc((size_t)2 * 512 * 4 * 256 * 2);
  unsigned short* NF1b  = (unsigned short*)alloc((size_t)2 * 8192 * 256 * 2);
  unsigned short* NF0b  = (unsigned short*)alloc((size_t)2 * 512 * 256 * 2);
  unsigned short* WB    = (unsigned short*)alloc((size_t)1196032 * 2);

  unsigned short* Wpt  = WB;
  unsigned short* WT0  = WB + 16384;
  unsigned short* WT1  = WB + 278528;
  unsigned short* WXT0 = WB + 802816;
  unsigned short* WNT0 = WB + 868352;
  unsigned short* WXT1 = WB + 933888;
  unsigned short* WNT1 = WB + 1064960;

  unsigned key0[2][2], key1[2][2];
  for (int mp = 0; mp < 2; ++mp)
    for (int li = 0; li < 2; ++li) {
      unsigned K0, K1;
      tf2x32(0u, 42u, 0u, (unsigned)(mp * 16 + li), K0, K1);
      tf2x32(K0, K1, 0u, 1u, key0[mp][li], key1[mp][li]);
    }

  transcast_kernel<<<4672, 256, 0, stream>>>(Wp, Wa1_0, Wa1_1, Wx_0, Wn_0,
                                             Wx_1, Wn_1, WB);
  frontier2_kernel<<<dim3(512, 1, 2), 256, 0, stream>>>(
      adjs, ids, nodes,
      key0[0][0], key1[0][0], key0[0][1], key1[0][1],
      key0[1][0], key1[1][0], key0[1][1], key1[1][1]);

  // prep ALL nodes once: P_all = bf16(feats @ Wp). MG=1 -> 3126 blocks (TLP).
  mfma_gemm<0, true, 4, 1><<<dim3(3126, 1, 1), 256, 0, stream>>>(
      feats, nullptr, Wpt, P_all, 128, 199999, 0, 0, 0, 0);

  // ---- L0 merged (big: x=frontier1/nb=frontier2; small: x=ids/nb=frontier1)
  tgemm_m<4, 2><<<dim3(68, 4, 2), 256, 0, stream>>>(
      P_all, nodes + 512, nodes, WT0, Tbig, T2, 64,
      139776, 139776, 131072, 4194304, 262144);
  aggsc_m<4, 4><<<dim3(2176, 1, 2), 256, 0, stream>>>(
      P_all, 0, nodes + 8704, nodes + 512, Tbig, T2, WT0 + 65536, wa2_0,
      AGbig, AG2, 2048, 139776, 139776, 4194304, 262144, 131072, 512,
      4194304, 262144);
  outg_m<128, 2><<<dim3(68, 4, 2), 256, 0, stream>>>(
      P_all, nodes + 512, nodes, AGbig, AG2, WXT0, WNT0, NF1b, NF0b, 64,
      139776, 139776, 4194304, 262144, 32768, 2097152, 131072);

  // ---- L1 (batched over mp): x=NF0b, nb=NF1b -> d_out
  mfma_gemm<1, false, 8, 1><<<dim3(8, 4, 2), 256, 0, stream>>>(
      NF0b, nullptr, WT1, T2, 512, 511, 131072, 0, 262144, 262144);
  // NF1b has 8192 NB rows per mp; MG=2 -> 32 rows/block -> 256 blocks. (R16 bug: was 16.)
  aggsc_m<8, 2><<<dim3(256, 1, 2), 256, 0, stream>>>(
      NF1b, 2097152, nullptr, nullptr, T2, T2, WT1 + 131072, wa2_1,
      AG2, AG2, 256, 0, 0, 262144, 262144, 262144, 512, 524288, 524288);
  outg_f32<256, 1><<<dim3(8, 4, 2), 256, 0, stream>>>(
      NF0b, AG2, WXT1, WNT1, out, 131072, 524288, 65536, 131072);
}